// Round 8
// baseline (217.920 us; speedup 1.0000x reference)
//
#include <hip/hip_runtime.h>
#include <hip/hip_bf16.h>

#define B_ 8
#define L_ 2048
#define DM 512
#define E_ 64
#define H_ 64
#define R_ 4
#define KC 3
#define BL (B_*L_)   // 16384
#define NX 132       // R + 2H
#define LC 128       // scan chunk length
#define NCH (L_/LC)  // 16 chunks

typedef __attribute__((ext_vector_type(8))) short bfrag;
typedef __attribute__((ext_vector_type(4))) float facc;

__device__ __forceinline__ unsigned short f2b(float f) {
  __hip_bfloat16 h = __float2bfloat16(f);
  return *reinterpret_cast<unsigned short*>(&h);
}
__device__ __forceinline__ bfrag ld_frag(const unsigned short* p) {
  bfrag t;
  __builtin_memcpy(&t, p, 16);
  return t;
}

// ---- K1 (MFMA, dbuf LDS): xz = x @ W_in ; cols 0..63 -> xp_pre[token][64], 64..127 -> resT
// BM=32, BN=128, BK=32. 512 blocks x 256 threads (4 waves: 2 m-tiles x 2 n-groups).
__global__ __launch_bounds__(256) void k_gemm_in(
    const float* __restrict__ x, const float* __restrict__ Win,
    float* __restrict__ xp_pre, float* __restrict__ resT)
{
  __shared__ unsigned short As[2][32][36];
  __shared__ unsigned short Bs[2][128][36];
  const int tid  = threadIdx.x;
  const int m0   = blockIdx.x * 32;
  const int b    = m0 >> 11;
  const int l0   = m0 & 2047;
  const int lane = tid & 63;
  const int wave = tid >> 6;
  const int mt   = wave & 1;        // m-tile (rows mt*16..+15)
  const int ng   = wave >> 1;       // n-group (tiles ng*4..ng*4+3)
  const int nl   = lane & 15;
  const int g    = lane >> 4;
  facc acc[4];
  #pragma unroll
  for (int j = 0; j < 4; ++j) acc[j] = (facc)(0.f);

  auto stage = [&](int sel, int k0) {
    {   // A: 32x32, 256 float4 tasks, 1/thread
      int r = tid >> 3, q = tid & 7;
      float4 v = *(const float4*)&x[(size_t)(m0 + r) * DM + k0 + 4 * q];
      ushort4 u;
      u.x = f2b(v.x); u.y = f2b(v.y); u.z = f2b(v.z); u.w = f2b(v.w);
      *(ushort4*)&As[sel][r][4 * q] = u;
    }
    #pragma unroll
    for (int p = 0; p < 4; ++p) {   // B: 32x128 transposed, 1024 tasks
      int fidx = tid + 256 * p;
      int r = fidx >> 5, cq = fidx & 31;
      float4 v = *(const float4*)&Win[(size_t)(k0 + r) * 128 + 4 * cq];
      Bs[sel][4 * cq + 0][r] = f2b(v.x);
      Bs[sel][4 * cq + 1][r] = f2b(v.y);
      Bs[sel][4 * cq + 2][r] = f2b(v.z);
      Bs[sel][4 * cq + 3][r] = f2b(v.w);
    }
  };

  stage(0, 0);
  __syncthreads();
  for (int it = 0; it < 16; ++it) {
    const int cur = it & 1;
    if (it + 1 < 16) stage(cur ^ 1, (it + 1) * 32);
    bfrag af = ld_frag(&As[cur][mt * 16 + nl][g * 8]);
    #pragma unroll
    for (int nt2 = 0; nt2 < 4; ++nt2) {
      bfrag bfr = ld_frag(&Bs[cur][(ng * 4 + nt2) * 16 + nl][g * 8]);
      acc[nt2] = __builtin_amdgcn_mfma_f32_16x16x32_bf16(af, bfr, acc[nt2], 0, 0, 0);
    }
    __syncthreads();
  }
  #pragma unroll
  for (int nt2 = 0; nt2 < 4; ++nt2) {
    facc a = acc[nt2];
    int c = (ng * 4 + nt2) * 16 + nl;
    int mrow = mt * 16 + 4 * g;
    if (c < 64) {
      #pragma unroll
      for (int r = 0; r < 4; ++r)
        xp_pre[(size_t)(m0 + mrow + r) * 64 + c] = a[r];
    } else {
      *(float4*)&resT[(size_t)(b * 64 + (c - 64)) * L_ + l0 + mrow] =
          make_float4(a[0], a[1], a[2], a[3]);
    }
  }
}

// ---- K2 (fused, MFMA): conv+silu -> xpT + bf16 A-tile ; [delta|B|C] = xp @ WF (W_dt folded) ;
// softplus -> deltaT. 256 blocks x 256 threads (4 waves: m-tile each, 12 n-tiles).
__global__ __launch_bounds__(256) void k_fused(
    const float* __restrict__ xp_pre,
    const float* __restrict__ conv_w, const float* __restrict__ conv_b,
    const float* __restrict__ Wx, const float* __restrict__ Wdt, const float* __restrict__ bdt,
    float* __restrict__ xpT, float* __restrict__ deltaT,
    float* __restrict__ Bm, float* __restrict__ Cm)
{
  __shared__ float raw[66][65];                // pre-conv xz rows l0-2..l0+63
  __shared__ unsigned short rawb[64][72];      // bf16 silu'd xp (A-tile), 144B rows
  __shared__ unsigned short WFb[192][40];      // bf16 W transposed [n][e], 80B rows
  const int tid = threadIdx.x;
  const int t0 = blockIdx.x * 64;
  const int b  = t0 >> 11;
  const int l0 = t0 & 2047;
  // stage raw (zero-pad l<0)
  for (int fidx = tid; fidx < 66 * 16; fidx += 256) {
    int r = fidx >> 4, cg = fidx & 15;
    int l = l0 - 2 + r;
    float4 v = make_float4(0.f, 0.f, 0.f, 0.f);
    if (l >= 0) v = *(const float4*)&xp_pre[((size_t)b * L_ + l) * 64 + cg * 4];
    raw[r][cg * 4 + 0] = v.x;
    raw[r][cg * 4 + 1] = v.y;
    raw[r][cg * 4 + 2] = v.z;
    raw[r][cg * 4 + 3] = v.w;
  }
  // stage WFb with W_dt fold (n = fidx>>6 is wave-uniform)
  for (int fidx = tid; fidx < 192 * 64; fidx += 256) {
    int n = fidx >> 6, e = fidx & 63;
    float v;
    if (n < 64) {
      v = 0.f;
      #pragma unroll
      for (int j = 0; j < R_; ++j)
        v = fmaf(Wx[e * NX + j], Wdt[j * 64 + n], v);
    } else if (n < 128) {
      v = Wx[e * NX + R_ + (n - 64)];
    } else {
      v = Wx[e * NX + R_ + 64 + (n - 128)];
    }
    WFb[n][e] = f2b(v);
  }
  __syncthreads();
  // conv + silu: thread -> (e, 16 tokens); write bf16 A-tile + xpT
  const int e  = tid & 63;
  const int tl = tid >> 6;
  const float w0 = conv_w[e * KC + 0], w1 = conv_w[e * KC + 1], w2 = conv_w[e * KC + 2];
  const float cb = conv_b[e];
  float cres[16];
  #pragma unroll
  for (int i = 0; i < 16; ++i) {
    int tok = tl * 16 + i;
    float a = cb;
    a = fmaf(raw[tok + 0][e], w0, a);
    a = fmaf(raw[tok + 1][e], w1, a);
    a = fmaf(raw[tok + 2][e], w2, a);
    cres[i] = a / (1.f + __expf(-a));
  }
  #pragma unroll
  for (int i = 0; i < 16; ++i) rawb[tl * 16 + i][e] = f2b(cres[i]);
  #pragma unroll
  for (int i = 0; i < 16; i += 4)
    *(float4*)&xpT[(size_t)(b * 64 + e) * L_ + l0 + tl * 16 + i] =
        make_float4(cres[i], cres[i + 1], cres[i + 2], cres[i + 3]);
  __syncthreads();
  // MFMA GEMM: M=64 (4 waves x 16), N=192 (12 tiles), K=64 (2 ksteps)
  const int wave = tid >> 6;
  const int lane = tid & 63;
  const int nl   = lane & 15;
  const int g    = lane >> 4;
  facc acc[12];
  #pragma unroll
  for (int j = 0; j < 12; ++j) acc[j] = (facc)(0.f);
  #pragma unroll
  for (int ks = 0; ks < 2; ++ks) {
    bfrag af = ld_frag(&rawb[wave * 16 + nl][ks * 32 + g * 8]);
    #pragma unroll
    for (int nt = 0; nt < 12; ++nt) {
      bfrag bfr = ld_frag(&WFb[nt * 16 + nl][ks * 32 + g * 8]);
      acc[nt] = __builtin_amdgcn_mfma_f32_16x16x32_bf16(af, bfr, acc[nt], 0, 0, 0);
    }
  }
  // epilogue: token = t0 + wave*16 + 4g + r ; col c = nt*16 + nl
  const int mrow = wave * 16 + 4 * g;
  #pragma unroll
  for (int nt = 0; nt < 12; ++nt) {
    facc a = acc[nt];
    int c = nt * 16 + nl;
    if (c < 64) {
      float bias = bdt[c];
      float d0 = a[0] + bias, d1 = a[1] + bias, d2 = a[2] + bias, d3 = a[3] + bias;
      float4 dv;
      dv.x = (d0 > 20.f) ? d0 : log1pf(__expf(d0));
      dv.y = (d1 > 20.f) ? d1 : log1pf(__expf(d1));
      dv.z = (d2 > 20.f) ? d2 : log1pf(__expf(d2));
      dv.w = (d3 > 20.f) ? d3 : log1pf(__expf(d3));
      *(float4*)&deltaT[(size_t)(b * 64 + c) * L_ + l0 + mrow] = dv;
    } else if (c < 128) {
      #pragma unroll
      for (int r = 0; r < 4; ++r)
        Bm[(size_t)(t0 + mrow + r) * 64 + (c - 64)] = a[r];
    } else {
      #pragma unroll
      for (int r = 0; r < 4; ++r)
        Cm[(size_t)(t0 + mrow + r) * 64 + (c - 128)] = a[r];
    }
  }
}

// ---- K3a: per-chunk summaries
__global__ __launch_bounds__(64) void k_scan1(
    const float* __restrict__ deltaT, const float* __restrict__ xpT,
    const float* __restrict__ Bm, const float* __restrict__ A_log,
    float* __restrict__ Ssum, float* __restrict__ Pp)
{
  __shared__ float dbuf[64], xbuf[64];
  const int blk = blockIdx.x;
  const int c = blk & (NCH - 1);
  const int e = (blk >> 4) & 63;
  const int b = blk >> 10;
  const int h = threadIdx.x;
  const float A = -__expf(A_log[e * 64 + h]);
  const size_t beL = (size_t)(b * 64 + e) * L_;
  float s = 0.f, sd = 0.f;
  for (int sub = 0; sub < LC / 64; ++sub) {
    const int l0 = c * LC + sub * 64;
    __syncthreads();
    dbuf[h] = deltaT[beL + l0 + h];
    xbuf[h] = xpT[beL + l0 + h];
    __syncthreads();
    #pragma unroll 4
    for (int k = 0; k < 64; ++k) {
      float dlt = dbuf[k];
      float w = dlt * xbuf[k];
      float Bh = Bm[(size_t)(b * L_ + l0 + k) * 64 + h];
      float dA = __expf(dlt * A);
      s = fmaf(dA, s, w * Bh);
      sd += dlt;
    }
  }
  const size_t idx = (size_t)blk * 64 + h;
  Ssum[idx] = s;
  Pp[idx]   = __expf(A * sd);
}

// ---- K3c: scan per chunk; entry state composed inline from Ssum/Pp; bf16 LDS-transpose reduction
__global__ __launch_bounds__(64) void k_scan3(
    const float* __restrict__ deltaT, const float* __restrict__ xpT,
    const float* __restrict__ resT,
    const float* __restrict__ Bm, const float* __restrict__ Cm,
    const float* __restrict__ A_log, const float* __restrict__ Dp,
    const float* __restrict__ Ssum, const float* __restrict__ Pp,
    float* __restrict__ yg)
{
  __shared__ unsigned short tile[64 * 68];
  __shared__ float dbuf[64], xbuf[64], rbuf[64];
  const int blk = blockIdx.x;
  const int c = blk & (NCH - 1);
  const int e = (blk >> 4) & 63;
  const int b = blk >> 10;
  const int h = threadIdx.x;
  const float A = -__expf(A_log[e * 64 + h]);
  const float Dv = Dp[e];
  const size_t beL = (size_t)(b * 64 + e) * L_;
  // compose entry state from chunk summaries 0..c-1
  float s = 0.f;
  const size_t sbase = ((size_t)(b * 64 + e) * NCH) * 64 + h;
  for (int cc = 0; cc < c; ++cc)
    s = fmaf(Pp[sbase + (size_t)cc * 64], s, Ssum[sbase + (size_t)cc * 64]);
  for (int sub = 0; sub < LC / 64; ++sub) {
    const int l0 = c * LC + sub * 64;
    __syncthreads();
    dbuf[h] = deltaT[beL + l0 + h];
    xbuf[h] = xpT[beL + l0 + h];
    rbuf[h] = resT[beL + l0 + h];
    __syncthreads();
    #pragma unroll 4
    for (int k = 0; k < 64; ++k) {
      float dlt = dbuf[k];
      float w = dlt * xbuf[k];
      const size_t off = (size_t)(b * L_ + l0 + k) * 64;
      float Bh = Bm[off + h];
      float Ch = Cm[off + h];
      float dA = __expf(dlt * A);
      s = fmaf(dA, s, w * Bh);
      tile[k * 68 + h] = f2b(s * Ch);
    }
    __syncthreads();
    float a0 = 0.f, a1 = 0.f, a2 = 0.f, a3 = 0.f;
    const ushort4* rp = (const ushort4*)&tile[h * 68];
    #pragma unroll
    for (int q = 0; q < 16; ++q) {
      ushort4 u = rp[q];
      a0 += __uint_as_float((unsigned)u.x << 16);
      a1 += __uint_as_float((unsigned)u.y << 16);
      a2 += __uint_as_float((unsigned)u.z << 16);
      a3 += __uint_as_float((unsigned)u.w << 16);
    }
    float sum = (a0 + a1) + (a2 + a3);
    float y = fmaf(xbuf[h], Dv, sum);
    y *= 1.0f / (1.0f + __expf(-rbuf[h]));
    yg[(size_t)(b * L_ + l0 + h) * 64 + e] = y;
  }
}

// ---- K4 (MFMA): out = yg @ W_out. BM=64, BN=128, K=64 single stage. 1024 blocks x 128 thr.
__global__ __launch_bounds__(128) void k_gemm_out(
    const float* __restrict__ yg, const float* __restrict__ Wout,
    float* __restrict__ out)
{
  __shared__ unsigned short As[64][68];
  __shared__ unsigned short Bs[128][68];
  const int tid  = threadIdx.x;
  const int m0   = (blockIdx.x & 255) * 64;
  const int n0   = (blockIdx.x >> 8) * 128;
  const int lane = tid & 63;
  const int wave = tid >> 6;
  const int nl   = lane & 15;
  const int g    = lane >> 4;
  #pragma unroll
  for (int p = 0; p < 8; ++p) {
    int fidx = tid + 128 * p;
    int r = fidx >> 4, q = fidx & 15;
    float4 v = *(const float4*)&yg[(size_t)(m0 + r) * 64 + 4 * q];
    ushort4 u;
    u.x = f2b(v.x); u.y = f2b(v.y); u.z = f2b(v.z); u.w = f2b(v.w);
    *(ushort4*)&As[r][4 * q] = u;
  }
  #pragma unroll
  for (int p = 0; p < 16; ++p) {
    int fidx = tid + 128 * p;
    int r = fidx >> 5, cq = fidx & 31;
    float4 v = *(const float4*)&Wout[(size_t)r * DM + n0 + 4 * cq];
    Bs[4 * cq + 0][r] = f2b(v.x);
    Bs[4 * cq + 1][r] = f2b(v.y);
    Bs[4 * cq + 2][r] = f2b(v.z);
    Bs[4 * cq + 3][r] = f2b(v.w);
  }
  __syncthreads();
  facc acc[2][8];
  #pragma unroll
  for (int i = 0; i < 2; ++i)
    #pragma unroll
    for (int j = 0; j < 8; ++j)
      acc[i][j] = (facc)(0.f);
  #pragma unroll
  for (int ks = 0; ks < 2; ++ks) {
    bfrag af0 = ld_frag(&As[wave * 32 + nl][ks * 32 + g * 8]);
    bfrag af1 = ld_frag(&As[wave * 32 + 16 + nl][ks * 32 + g * 8]);
    #pragma unroll
    for (int nt = 0; nt < 8; ++nt) {
      bfrag bfr = ld_frag(&Bs[nt * 16 + nl][ks * 32 + g * 8]);
      acc[0][nt] = __builtin_amdgcn_mfma_f32_16x16x32_bf16(af0, bfr, acc[0][nt], 0, 0, 0);
      acc[1][nt] = __builtin_amdgcn_mfma_f32_16x16x32_bf16(af1, bfr, acc[1][nt], 0, 0, 0);
    }
  }
  #pragma unroll
  for (int mt = 0; mt < 2; ++mt) {
    int mrow = m0 + wave * 32 + mt * 16 + 4 * g;
    #pragma unroll
    for (int nt = 0; nt < 8; ++nt) {
      facc a = acc[mt][nt];
      int c = n0 + nt * 16 + nl;
      #pragma unroll
      for (int r = 0; r < 4; ++r)
        out[(size_t)(mrow + r) * DM + c] = a[r];
    }
  }
}

extern "C" void kernel_launch(void* const* d_in, const int* in_sizes, int n_in,
                              void* d_out, int out_size, void* d_ws, size_t ws_size,
                              hipStream_t stream) {
  const float* x      = (const float*)d_in[0];
  const float* Win    = (const float*)d_in[1];
  const float* conv_w = (const float*)d_in[2];
  const float* conv_b = (const float*)d_in[3];
  const float* Wx     = (const float*)d_in[4];
  const float* Wdt    = (const float*)d_in[5];
  const float* bdt    = (const float*)d_in[6];
  const float* A_log  = (const float*)d_in[7];
  const float* Dp     = (const float*)d_in[8];
  const float* Wout   = (const float*)d_in[9];
  float* out = (float*)d_out;

  float* ws = (float*)d_ws;
  const size_t SZ = (size_t)BL * 64;
  const size_t CH = (size_t)B_ * E_ * NCH * 64;
  float* xp_pre = ws + 0 * SZ;
  float* resT   = ws + 1 * SZ;
  float* xpT    = ws + 2 * SZ;
  float* deltaT = ws + 3 * SZ;
  float* Bm     = ws + 4 * SZ;
  float* Cm     = ws + 5 * SZ;
  float* yg     = ws + 6 * SZ;
  float* Ssum   = ws + 7 * SZ;
  float* Pp     = ws + 7 * SZ + 1 * CH;

  hipLaunchKernelGGL(k_gemm_in,  dim3(BL / 32),       dim3(256), 0, stream, x, Win, xp_pre, resT);
  hipLaunchKernelGGL(k_fused,    dim3(BL / 64),       dim3(256), 0, stream,
                     xp_pre, conv_w, conv_b, Wx, Wdt, bdt, xpT, deltaT, Bm, Cm);
  hipLaunchKernelGGL(k_scan1,    dim3(B_ * E_ * NCH), dim3(64),  0, stream,
                     deltaT, xpT, Bm, A_log, Ssum, Pp);
  hipLaunchKernelGGL(k_scan3,    dim3(B_ * E_ * NCH), dim3(64),  0, stream,
                     deltaT, xpT, resT, Bm, Cm, A_log, Dp, Ssum, Pp, yg);
  hipLaunchKernelGGL(k_gemm_out, dim3(1024),          dim3(128), 0, stream, yg, Wout, out);
}

// Round 10
// 213.495 us; speedup vs baseline: 1.0207x; 1.0207x over previous
//
#include <hip/hip_runtime.h>
#include <hip/hip_bf16.h>

#define B_ 8
#define L_ 2048
#define DM 512
#define E_ 64
#define H_ 64
#define R_ 4
#define KC 3
#define BL (B_*L_)   // 16384
#define NX 132       // R + 2H
#define LC 128       // scan chunk length
#define NCH (L_/LC)  // 16 chunks

typedef __attribute__((ext_vector_type(8))) short bfrag;
typedef __attribute__((ext_vector_type(4))) float facc;

__device__ __forceinline__ unsigned short f2b(float f) {
  __hip_bfloat16 h = __float2bfloat16(f);
  return *reinterpret_cast<unsigned short*>(&h);
}
__device__ __forceinline__ float b2f16(unsigned short u) {
  return __uint_as_float((unsigned)u << 16);
}
__device__ __forceinline__ bfrag ld_frag(const unsigned short* p) {
  bfrag t;
  __builtin_memcpy(&t, p, 16);
  return t;
}

// ---- K0: fold W_dt into W_x -> WFT bf16 [192][64] (n-major). 192 blocks x 64 thr.
__global__ __launch_bounds__(64) void k_wfuse(
    const float* __restrict__ Wx, const float* __restrict__ Wdt,
    unsigned short* __restrict__ WFT)
{
  const int n = blockIdx.x;
  const int e = threadIdx.x;
  float v;
  if (n < 64) {
    v = 0.f;
    #pragma unroll
    for (int j = 0; j < R_; ++j)
      v = fmaf(Wx[e * NX + j], Wdt[j * 64 + n], v);
  } else if (n < 128) {
    v = Wx[e * NX + R_ + (n - 64)];
  } else {
    v = Wx[e * NX + R_ + 64 + (n - 128)];
  }
  WFT[n * 64 + e] = f2b(v);
}

// ---- K1 (MFMA, dbuf LDS — SAFE: staging always writes the other buffer):
// xz = x @ W_in ; cols 0..63 -> xp_pre[token][64], 64..127 -> resT
__global__ __launch_bounds__(256) void k_gemm_in(
    const float* __restrict__ x, const float* __restrict__ Win,
    float* __restrict__ xp_pre, float* __restrict__ resT)
{
  __shared__ unsigned short As[2][32][36];
  __shared__ unsigned short Bs[2][128][36];
  const int tid  = threadIdx.x;
  const int m0   = blockIdx.x * 32;
  const int b    = m0 >> 11;
  const int l0   = m0 & 2047;
  const int lane = tid & 63;
  const int wave = tid >> 6;
  const int mt   = wave & 1;
  const int ng   = wave >> 1;
  const int nl   = lane & 15;
  const int g    = lane >> 4;
  facc acc[4];
  #pragma unroll
  for (int j = 0; j < 4; ++j) acc[j] = (facc)(0.f);

  auto stage = [&](int sel, int k0) {
    {
      int r = tid >> 3, q = tid & 7;
      float4 v = *(const float4*)&x[(size_t)(m0 + r) * DM + k0 + 4 * q];
      ushort4 u;
      u.x = f2b(v.x); u.y = f2b(v.y); u.z = f2b(v.z); u.w = f2b(v.w);
      *(ushort4*)&As[sel][r][4 * q] = u;
    }
    #pragma unroll
    for (int p = 0; p < 4; ++p) {
      int fidx = tid + 256 * p;
      int r = fidx >> 5, cq = fidx & 31;
      float4 v = *(const float4*)&Win[(size_t)(k0 + r) * 128 + 4 * cq];
      Bs[sel][4 * cq + 0][r] = f2b(v.x);
      Bs[sel][4 * cq + 1][r] = f2b(v.y);
      Bs[sel][4 * cq + 2][r] = f2b(v.z);
      Bs[sel][4 * cq + 3][r] = f2b(v.w);
    }
  };

  stage(0, 0);
  __syncthreads();
  for (int it = 0; it < 16; ++it) {
    const int cur = it & 1;
    if (it + 1 < 16) stage(cur ^ 1, (it + 1) * 32);
    bfrag af = ld_frag(&As[cur][mt * 16 + nl][g * 8]);
    #pragma unroll
    for (int nt2 = 0; nt2 < 4; ++nt2) {
      bfrag bfr = ld_frag(&Bs[cur][(ng * 4 + nt2) * 16 + nl][g * 8]);
      acc[nt2] = __builtin_amdgcn_mfma_f32_16x16x32_bf16(af, bfr, acc[nt2], 0, 0, 0);
    }
    __syncthreads();
  }
  #pragma unroll
  for (int nt2 = 0; nt2 < 4; ++nt2) {
    facc a = acc[nt2];
    int c = (ng * 4 + nt2) * 16 + nl;
    int mrow = mt * 16 + 4 * g;
    if (c < 64) {
      #pragma unroll
      for (int r = 0; r < 4; ++r)
        xp_pre[(size_t)(m0 + mrow + r) * 64 + c] = a[r];
    } else {
      *(float4*)&resT[(size_t)(b * 64 + (c - 64)) * L_ + l0 + mrow] =
          make_float4(a[0], a[1], a[2], a[3]);
    }
  }
}

// ---- K2 (fused, MFMA — single-shot staging, 2 barriers, no re-staging):
// conv+silu -> xpT + bf16 A-tile ; [delta|B|C] = xp @ WF ; softplus -> deltaT ; B/C bf16.
__global__ __launch_bounds__(256) void k_fused(
    const float* __restrict__ xp_pre,
    const float* __restrict__ conv_w, const float* __restrict__ conv_b,
    const unsigned short* __restrict__ WFT, const float* __restrict__ bdt,
    float* __restrict__ xpT, float* __restrict__ deltaT,
    unsigned short* __restrict__ Bmh, unsigned short* __restrict__ Cmh)
{
  __shared__ float raw[66][65];
  __shared__ unsigned short rawb[64][72];     // 144B rows, 16B aligned
  __shared__ unsigned short WFb[192][72];     // FULL K=64 rows: no aliasing, staged ONCE
  const int tid = threadIdx.x;
  const int t0 = blockIdx.x * 64;
  const int b  = t0 >> 11;
  const int l0 = t0 & 2047;
  // stage raw (zero-pad l<0)
  for (int fidx = tid; fidx < 66 * 16; fidx += 256) {
    int r = fidx >> 4, cg = fidx & 15;
    int l = l0 - 2 + r;
    float4 v = make_float4(0.f, 0.f, 0.f, 0.f);
    if (l >= 0) v = *(const float4*)&xp_pre[((size_t)b * L_ + l) * 64 + cg * 4];
    raw[r][cg * 4 + 0] = v.x;
    raw[r][cg * 4 + 1] = v.y;
    raw[r][cg * 4 + 2] = v.z;
    raw[r][cg * 4 + 3] = v.w;
  }
  // stage full WFb (192 rows x 64 k), ushort4 chunks; offsets 4*jq <= 60 < 72
  for (int i4 = tid; i4 < 192 * 16; i4 += 256) {
    int n = i4 >> 4, jq = i4 & 15;
    *(ushort4*)&WFb[n][jq * 4] = *(const ushort4*)&WFT[n * 64 + jq * 4];
  }
  __syncthreads();
  // conv + silu: thread -> (e, 16 tokens); write bf16 A-tile + xpT
  const int e  = tid & 63;
  const int tl = tid >> 6;
  const float w0 = conv_w[e * KC + 0], w1 = conv_w[e * KC + 1], w2 = conv_w[e * KC + 2];
  const float cb = conv_b[e];
  float cres[16];
  #pragma unroll
  for (int i = 0; i < 16; ++i) {
    int tok = tl * 16 + i;
    float a = cb;
    a = fmaf(raw[tok + 0][e], w0, a);
    a = fmaf(raw[tok + 1][e], w1, a);
    a = fmaf(raw[tok + 2][e], w2, a);
    cres[i] = a / (1.f + __expf(-a));
  }
  #pragma unroll
  for (int i = 0; i < 16; ++i) rawb[tl * 16 + i][e] = f2b(cres[i]);
  #pragma unroll
  for (int i = 0; i < 16; i += 4)
    *(float4*)&xpT[(size_t)(b * 64 + e) * L_ + l0 + tl * 16 + i] =
        make_float4(cres[i], cres[i + 1], cres[i + 2], cres[i + 3]);
  __syncthreads();
  // MFMA GEMM: M=64 (4 waves), N=192 (12 tiles), K=64 (2 ksteps) — all LDS read-only now
  const int wave = tid >> 6;
  const int lane = tid & 63;
  const int nl   = lane & 15;
  const int g    = lane >> 4;
  facc acc[12];
  #pragma unroll
  for (int j = 0; j < 12; ++j) acc[j] = (facc)(0.f);
  #pragma unroll
  for (int ks = 0; ks < 2; ++ks) {
    bfrag af = ld_frag(&rawb[wave * 16 + nl][ks * 32 + g * 8]);
    #pragma unroll
    for (int nt = 0; nt < 12; ++nt) {
      bfrag bfr = ld_frag(&WFb[nt * 16 + nl][ks * 32 + g * 8]);
      acc[nt] = __builtin_amdgcn_mfma_f32_16x16x32_bf16(af, bfr, acc[nt], 0, 0, 0);
    }
  }
  const int mrow = wave * 16 + 4 * g;
  #pragma unroll
  for (int nt = 0; nt < 12; ++nt) {
    facc a = acc[nt];
    int c = nt * 16 + nl;
    if (c < 64) {
      float bias = bdt[c];
      float d0 = a[0] + bias, d1 = a[1] + bias, d2 = a[2] + bias, d3 = a[3] + bias;
      float4 dv;
      dv.x = (d0 > 20.f) ? d0 : log1pf(__expf(d0));
      dv.y = (d1 > 20.f) ? d1 : log1pf(__expf(d1));
      dv.z = (d2 > 20.f) ? d2 : log1pf(__expf(d2));
      dv.w = (d3 > 20.f) ? d3 : log1pf(__expf(d3));
      *(float4*)&deltaT[(size_t)(b * 64 + c) * L_ + l0 + mrow] = dv;
    } else if (c < 128) {
      #pragma unroll
      for (int r = 0; r < 4; ++r)
        Bmh[(size_t)(t0 + mrow + r) * 64 + (c - 64)] = f2b(a[r]);
    } else {
      #pragma unroll
      for (int r = 0; r < 4; ++r)
        Cmh[(size_t)(t0 + mrow + r) * 64 + (c - 128)] = f2b(a[r]);
    }
  }
}

// ---- K3a: per-chunk summaries. 4 waves/block, wave-private LDS, NO block barriers.
__global__ __launch_bounds__(256) void k_scan1(
    const float* __restrict__ deltaT, const float* __restrict__ xpT,
    const unsigned short* __restrict__ Bmh, const float* __restrict__ A_log,
    float* __restrict__ Ssum, float* __restrict__ Pp)
{
  __shared__ float dbufA[4][64], xbufA[4][64];
  const int tid  = threadIdx.x;
  const int wv   = tid >> 6;
  const int h    = tid & 63;
  const int id = blockIdx.x * 4 + wv;
  const int c = id & (NCH - 1);
  const int e = (id >> 4) & 63;
  const int b = id >> 10;
  const float A = -__expf(A_log[e * 64 + h]);
  const size_t beL = (size_t)(b * 64 + e) * L_;
  float* dbuf = dbufA[wv];
  float* xbuf = xbufA[wv];
  float s = 0.f, sd = 0.f;
  for (int sub = 0; sub < LC / 64; ++sub) {
    const int l0 = c * LC + sub * 64;
    dbuf[h] = deltaT[beL + l0 + h];
    xbuf[h] = xpT[beL + l0 + h];
    __builtin_amdgcn_wave_barrier();   // intra-wave DS ordering is HW-guaranteed; this pins the compiler
    #pragma unroll 4
    for (int k = 0; k < 64; ++k) {
      float dlt = dbuf[k];
      float w = dlt * xbuf[k];
      float Bh = b2f16(Bmh[(size_t)(b * L_ + l0 + k) * 64 + h]);
      s = fmaf(__expf(dlt * A), s, w * Bh);
      sd += dlt;
    }
    __builtin_amdgcn_wave_barrier();
  }
  const size_t idx = (size_t)id * 64 + h;
  Ssum[idx] = s;
  Pp[idx]   = __expf(A * sd);
}

// ---- K3c: scan per chunk. 4 waves/block, wave-private LDS, NO block barriers.
// Entry state composed inline; 16-row bf16 tile + shuffle reduce; coalesced ygT output.
__global__ __launch_bounds__(256) void k_scan3(
    const float* __restrict__ deltaT, const float* __restrict__ xpT,
    const float* __restrict__ resT,
    const unsigned short* __restrict__ Bmh, const unsigned short* __restrict__ Cmh,
    const float* __restrict__ A_log, const float* __restrict__ Dp,
    const float* __restrict__ Ssum, const float* __restrict__ Pp,
    float* __restrict__ ygT)
{
  __shared__ unsigned short tileA[4][16][68];
  __shared__ float dbufA[4][64], xbufA[4][64], rbufA[4][64];
  const int tid  = threadIdx.x;
  const int wv   = tid >> 6;
  const int h    = tid & 63;
  const int id = blockIdx.x * 4 + wv;
  const int c = id & (NCH - 1);
  const int e = (id >> 4) & 63;
  const int b = id >> 10;
  const float A = -__expf(A_log[e * 64 + h]);
  const float Dv = Dp[e];
  const size_t beL = (size_t)(b * 64 + e) * L_;
  unsigned short (*tile)[68] = tileA[wv];
  float* dbuf = dbufA[wv];
  float* xbuf = xbufA[wv];
  float* rbuf = rbufA[wv];
  // compose entry state from chunk summaries 0..c-1 (global reads only)
  float s = 0.f;
  const size_t sbase = (size_t)(id & ~(NCH - 1)) * 64 + h;
  for (int cc = 0; cc < c; ++cc)
    s = fmaf(Pp[sbase + (size_t)cc * 64], s, Ssum[sbase + (size_t)cc * 64]);
  for (int sub = 0; sub < LC / 64; ++sub) {
    const int l0 = c * LC + sub * 64;
    dbuf[h] = deltaT[beL + l0 + h];
    xbuf[h] = xpT[beL + l0 + h];
    rbuf[h] = resT[beL + l0 + h];
    __builtin_amdgcn_wave_barrier();
    for (int k16 = 0; k16 < 4; ++k16) {
      #pragma unroll
      for (int kk = 0; kk < 16; ++kk) {
        const int k = k16 * 16 + kk;
        float dlt = dbuf[k];
        float w = dlt * xbuf[k];
        const size_t off = (size_t)(b * L_ + l0 + k) * 64;
        float Bh = b2f16(Bmh[off + h]);
        float Ch = b2f16(Cmh[off + h]);
        s = fmaf(__expf(dlt * A), s, w * Bh);
        tile[kk][h] = f2b(s * Ch);
      }
      __builtin_amdgcn_wave_barrier();
      // lane h: row r = h&15, quarter q = h>>4; sum 16 values then combine quarters
      const int r = h & 15, q = h >> 4;
      float part = 0.f;
      const ushort4* rp = (const ushort4*)&tile[r][q * 16];
      #pragma unroll
      for (int jq = 0; jq < 4; ++jq) {
        ushort4 u = rp[jq];
        part += b2f16(u.x) + b2f16(u.y) + b2f16(u.z) + b2f16(u.w);
      }
      part += __shfl_xor(part, 16, 64);
      part += __shfl_xor(part, 32, 64);
      if (q == 0) {
        const int lk = k16 * 16 + r;
        float y = fmaf(xbuf[lk], Dv, part);
        y *= 1.0f / (1.0f + __expf(-rbuf[lk]));
        ygT[beL + l0 + lk] = y;
      }
      __builtin_amdgcn_wave_barrier();
    }
  }
}

// ---- K4 (MFMA): out = ygT^T @ W_out. Single-shot staging + 1 barrier. 1024 blocks x 128 thr.
__global__ __launch_bounds__(128) void k_gemm_out(
    const float* __restrict__ ygT, const float* __restrict__ Wout,
    float* __restrict__ out)
{
  __shared__ unsigned short As[64][68];
  __shared__ unsigned short Bs[128][68];
  const int tid  = threadIdx.x;
  const int m0   = (blockIdx.x & 255) * 64;
  const int n0   = (blockIdx.x >> 8) * 128;
  const int b    = m0 >> 11;
  const int l0   = m0 & 2047;
  const int lane = tid & 63;
  const int wave = tid >> 6;
  const int nl   = lane & 15;
  const int g    = lane >> 4;
  #pragma unroll
  for (int p = 0; p < 8; ++p) {
    int fidx = tid + 128 * p;              // 0..1023
    int e = fidx >> 4, q = fidx & 15;
    float4 v = *(const float4*)&ygT[(size_t)(b * 64 + e) * L_ + l0 + 4 * q];
    As[4 * q + 0][e] = f2b(v.x);
    As[4 * q + 1][e] = f2b(v.y);
    As[4 * q + 2][e] = f2b(v.z);
    As[4 * q + 3][e] = f2b(v.w);
  }
  #pragma unroll
  for (int p = 0; p < 16; ++p) {
    int fidx = tid + 128 * p;
    int r = fidx >> 5, cq = fidx & 31;
    float4 v = *(const float4*)&Wout[(size_t)r * DM + n0 + 4 * cq];
    Bs[4 * cq + 0][r] = f2b(v.x);
    Bs[4 * cq + 1][r] = f2b(v.y);
    Bs[4 * cq + 2][r] = f2b(v.z);
    Bs[4 * cq + 3][r] = f2b(v.w);
  }
  __syncthreads();
  facc acc[2][8];
  #pragma unroll
  for (int i = 0; i < 2; ++i)
    #pragma unroll
    for (int j = 0; j < 8; ++j)
      acc[i][j] = (facc)(0.f);
  #pragma unroll
  for (int ks = 0; ks < 2; ++ks) {
    bfrag af0 = ld_frag(&As[wave * 32 + nl][ks * 32 + g * 8]);
    bfrag af1 = ld_frag(&As[wave * 32 + 16 + nl][ks * 32 + g * 8]);
    #pragma unroll
    for (int nt = 0; nt < 8; ++nt) {
      bfrag bfr = ld_frag(&Bs[nt * 16 + nl][ks * 32 + g * 8]);
      acc[0][nt] = __builtin_amdgcn_mfma_f32_16x16x32_bf16(af0, bfr, acc[0][nt], 0, 0, 0);
      acc[1][nt] = __builtin_amdgcn_mfma_f32_16x16x32_bf16(af1, bfr, acc[1][nt], 0, 0, 0);
    }
  }
  #pragma unroll
  for (int mt = 0; mt < 2; ++mt) {
    int mrow = m0 + wave * 32 + mt * 16 + 4 * g;
    #pragma unroll
    for (int nt = 0; nt < 8; ++nt) {
      facc a = acc[mt][nt];
      int c = n0 + nt * 16 + nl;
      #pragma unroll
      for (int r = 0; r < 4; ++r)
        out[(size_t)(mrow + r) * DM + c] = a[r];
    }
  }
}

extern "C" void kernel_launch(void* const* d_in, const int* in_sizes, int n_in,
                              void* d_out, int out_size, void* d_ws, size_t ws_size,
                              hipStream_t stream) {
  const float* x      = (const float*)d_in[0];
  const float* Win    = (const float*)d_in[1];
  const float* conv_w = (const float*)d_in[2];
  const float* conv_b = (const float*)d_in[3];
  const float* Wx     = (const float*)d_in[4];
  const float* Wdt    = (const float*)d_in[5];
  const float* bdt    = (const float*)d_in[6];
  const float* A_log  = (const float*)d_in[7];
  const float* Dp     = (const float*)d_in[8];
  const float* Wout   = (const float*)d_in[9];
  float* out = (float*)d_out;

  float* ws = (float*)d_ws;
  const size_t SZ = (size_t)BL * 64;              // 1M floats
  const size_t CH = (size_t)B_ * E_ * NCH * 64;   // 512K floats
  float* xp_pre = ws + 0 * SZ;
  float* resT   = ws + 1 * SZ;
  float* xpT    = ws + 2 * SZ;
  float* deltaT = ws + 3 * SZ;
  unsigned short* Bmh = (unsigned short*)(ws + 4 * SZ);
  unsigned short* Cmh = Bmh + SZ;
  float* ygT    = ws + 5 * SZ;
  float* Ssum   = ws + 6 * SZ;
  float* Pp     = ws + 6 * SZ + 1 * CH;
  unsigned short* WFT = (unsigned short*)(ws + 6 * SZ + 2 * CH);

  hipLaunchKernelGGL(k_wfuse,    dim3(192),               dim3(64),  0, stream, Wx, Wdt, WFT);
  hipLaunchKernelGGL(k_gemm_in,  dim3(BL / 32),           dim3(256), 0, stream, x, Win, xp_pre, resT);
  hipLaunchKernelGGL(k_fused,    dim3(BL / 64),           dim3(256), 0, stream,
                     xp_pre, conv_w, conv_b, WFT, bdt, xpT, deltaT, Bmh, Cmh);
  hipLaunchKernelGGL(k_scan1,    dim3(B_ * E_ * NCH / 4), dim3(256), 0, stream,
                     deltaT, xpT, Bmh, A_log, Ssum, Pp);
  hipLaunchKernelGGL(k_scan3,    dim3(B_ * E_ * NCH / 4), dim3(256), 0, stream,
                     deltaT, xpT, resT, Bmh, Cmh, A_log, Dp, Ssum, Pp, ygT);
  hipLaunchKernelGGL(k_gemm_out, dim3(1024),              dim3(128), 0, stream, ygT, Wout, out);
}